// Round 4
// baseline (2642.896 us; speedup 1.0000x reference)
//
#include <hip/hip_runtime.h>
#include <math.h>

#define T 256
#define RS 36          // row stride (floats), even -> float2-aligned windows
#define PSA 720        // A plane stride = 20 rows * RS
#define PSB 648        // B plane stride = 18 rows * RS

#define OFF_B   5760               // A: 8 planes * PSA
#define OFF_ROT (OFF_B + 10368)    // B: 16 planes * PSB
#define OFF_ANG (OFF_ROT + 96)
#define OFF_Q   (OFF_ANG + 4)
#define OFF_RED (OFF_Q + 4)
#define LDS_FLOATS (OFF_RED + 16)  // 16248 floats = 64992 B -> 2 blocks/CU

// 2-pixel-wide 3x3 conv micro-kernel: reads 3x4 window per ic as float2 pairs
template <int CIN, int COUT, int PSI>
__device__ __forceinline__ void conv2px(const float* __restrict__ ib,
                                        const float* __restrict__ wg,
                                        const float* __restrict__ bg,
                                        float* __restrict__ acc0,
                                        float* __restrict__ acc1) {
#pragma unroll
    for (int oc = 0; oc < COUT; ++oc) { acc0[oc] = bg[oc]; acc1[oc] = bg[oc]; }
#pragma unroll
    for (int ic = 0; ic < CIN; ++ic) {
        float w[12];
#pragma unroll
        for (int ky = 0; ky < 3; ++ky) {
            const float2 u = *reinterpret_cast<const float2*>(ib + ic * PSI + ky * RS);
            const float2 v = *reinterpret_cast<const float2*>(ib + ic * PSI + ky * RS + 2);
            w[ky * 4 + 0] = u.x; w[ky * 4 + 1] = u.y;
            w[ky * 4 + 2] = v.x; w[ky * 4 + 3] = v.y;
        }
#pragma unroll
        for (int oc = 0; oc < COUT; ++oc) {
            const float* wp = wg + (oc * CIN + ic) * 9;   // uniform -> s_load
#pragma unroll
            for (int ky = 0; ky < 3; ++ky)
#pragma unroll
                for (int kx = 0; kx < 3; ++kx) {
                    acc0[oc] = fmaf(wp[ky * 3 + kx], w[ky * 4 + kx],     acc0[oc]);
                    acc1[oc] = fmaf(wp[ky * 3 + kx], w[ky * 4 + kx + 1], acc1[oc]);
                }
        }
    }
}

__global__ __launch_bounds__(T) void fused_kernel(
    const float* __restrict__ x,
    const float* __restrict__ c1w, const float* __restrict__ c1b,
    const float* __restrict__ c2w, const float* __restrict__ c2b,
    const float* __restrict__ fcw, const float* __restrict__ fcb,
    const float* __restrict__ qw,
    const float* __restrict__ f2w, const float* __restrict__ f2b,
    const float* __restrict__ d1w, const float* __restrict__ d1b,
    const float* __restrict__ d2w, const float* __restrict__ d2b,
    float* __restrict__ out) {
    __shared__ float lds[LDS_FLOATS];
    float* A   = lds;            // x window (3 planes) / h3 window (8 planes), 20 rows
    float* Bf  = lds + OFF_B;    // conv1/dconv1 out, 16 planes, 18 rows
    float* ROT = lds + OFF_ROT;

    const int tid = threadIdx.x;
    const int b   = blockIdx.x;

    for (int i = tid; i < LDS_FLOATS; i += T) lds[i] = 0.f;   // halos must be 0
    __syncthreads();

    if (tid < 12) {   // Rot matrices (batch-independent, tiny)
        float phi = qw[tid * 3 + 0], theta = qw[tid * 3 + 1], omega = qw[tid * 3 + 2];
        float a = 0.5f * (phi + omega), d = 0.5f * (phi - omega);
        float st, ct; sincosf(0.5f * theta, &st, &ct);
        float sa, ca; sincosf(a, &sa, &ca);
        float sd, cd; sincosf(d, &sd, &cd);
        float* o = ROT + tid * 8;
        o[0] = ct * ca;  o[1] = -ct * sa;
        o[2] = -st * cd; o[3] = -st * sd;
        o[4] = st * cd;  o[5] = -st * sd;
        o[6] = ct * ca;  o[7] = ct * sa;
    }

    float part[4] = {0.f, 0.f, 0.f, 0.f};

    // ================= encoder: 2 bands of 16 rows ==========================
    for (int band = 0; band < 2; ++band) {
        const int y0 = band * 16;

        // load x rows y0-2..y0+17 (3ch x 20 rows), OOB -> 0
        for (int i = tid; i < 1920; i += T) {
            int c = i / 640, rem = i - c * 640, r = rem >> 5, cx = rem & 31;
            int gy = y0 - 2 + r;
            float v = (gy >= 0 && gy < 32) ? x[b * 3072 + c * 1024 + gy * 32 + cx] : 0.f;
            A[c * PSA + r * RS + 1 + cx] = v;
        }
        __syncthreads();

        // conv1 3->16 rows y0-1..y0+16 (18 rows x 16 units)
        for (int u = tid; u < 288; u += T) {
            const int r1 = u >> 4, xb = (u & 15) * 2;
            const int gy = y0 - 1 + r1;
            float acc0[16], acc1[16];
            conv2px<3, 16, PSA>(A + r1 * RS + xb, c1w, c1b, acc0, acc1);
            const bool oob = (gy < 0) | (gy > 31);
            float* ob = Bf + r1 * RS + 1 + xb;
#pragma unroll
            for (int oc = 0; oc < 16; ++oc) {
                ob[oc * PSB]     = oob ? 0.f : fmaxf(acc0[oc], 0.f);
                ob[oc * PSB + 1] = oob ? 0.f : fmaxf(acc1[oc], 0.f);
            }
        }
        __syncthreads();

        // conv2 16->8 on band rows + fc partial fold (256 units == T)
        {
            const int r = tid >> 4, xb = (tid & 15) * 2;
            float acc0[8], acc1[8];
            conv2px<16, 8, PSB>(Bf + r * RS + xb, c2w, c2b, acc0, acc1);
            const int gj = (y0 + r) * 32 + xb;
#pragma unroll
            for (int oc = 0; oc < 8; ++oc) {
                const float h0 = fmaxf(acc0[oc], 0.f);
                const float h1 = fmaxf(acc1[oc], 0.f);
#pragma unroll
                for (int o = 0; o < 4; ++o) {
                    const float2 wv = *reinterpret_cast<const float2*>(
                        fcw + o * 8192 + oc * 1024 + gj);
                    part[o] = fmaf(h0, wv.x, fmaf(h1, wv.y, part[o]));
                }
            }
        }
        __syncthreads();
    }

    // ================= fc reduce -> angles ==================================
#pragma unroll
    for (int off = 32; off; off >>= 1)
#pragma unroll
        for (int o = 0; o < 4; ++o)
            part[o] += __shfl_down(part[o], off);
    if ((tid & 63) == 0) {
        int wid = tid >> 6;
#pragma unroll
        for (int o = 0; o < 4; ++o) lds[OFF_RED + wid * 4 + o] = part[o];
    }
    __syncthreads();
    if (tid == 0) {
#pragma unroll
        for (int o = 0; o < 4; ++o) {
            float s = fcb[o];
            for (int w = 0; w < 4; ++w) s += lds[OFF_RED + w * 4 + o];
            lds[OFF_ANG + o] = s;
        }
    }
    __syncthreads();

    // ================= 4-qubit statevector sim (wave 0) =====================
    if (tid < 64) {
        const int s = tid & 15;
        float re = (s == 0) ? 1.f : 0.f, im = 0.f;
#pragma unroll
        for (int w = 0; w < 4; ++w) {
            float a = lds[OFF_ANG + w] * 0.5f;
            float sn, c; sincosf(a, &sn, &c);
            int stride = 1 << (3 - w);
            float pr = __shfl_xor(re, stride);
            float pi = __shfl_xor(im, stride);
            float nre = c * re + sn * pi;
            float nim = c * im - sn * pr;
            re = nre; im = nim;
        }
#pragma unroll
        for (int l = 0; l < 3; ++l) {
#pragma unroll
            for (int w = 0; w < 4; ++w) {
                const float* U = ROT + (l * 4 + w) * 8;
                int stride = 1 << (3 - w);
                bool bit = (s & stride) != 0;
                float pr = __shfl_xor(re, stride);
                float pi = __shfl_xor(im, stride);
                float cAr = bit ? U[6] : U[0], cAi = bit ? U[7] : U[1];
                float cBr = bit ? U[4] : U[2], cBi = bit ? U[5] : U[3];
                float nre = cAr * re - cAi * im + cBr * pr - cBi * pi;
                float nim = cAr * im + cAi * re + cBr * pi + cBi * pr;
                re = nre; im = nim;
            }
            const int r = (l % 3) + 1;
#pragma unroll
            for (int w = 0; w < 4; ++w) {
                int cs = 1 << (3 - w);
                int ts = 1 << (3 - ((w + r) & 3));
                float pr = __shfl_xor(re, ts);
                float pi = __shfl_xor(im, ts);
                if (s & cs) { re = pr; im = pi; }
            }
        }
        float pprob = re * re + im * im;
        float ev[4];
#pragma unroll
        for (int w = 0; w < 4; ++w)
            ev[w] = (s & (1 << (3 - w))) ? -pprob : pprob;
#pragma unroll
        for (int m = 1; m <= 8; m <<= 1)
#pragma unroll
            for (int w = 0; w < 4; ++w)
                ev[w] += __shfl_xor(ev[w], m);
        if (tid == 0) {
#pragma unroll
            for (int w = 0; w < 4; ++w) lds[OFF_Q + w] = ev[w];
        }
    }
    __syncthreads();

    const float q0 = lds[OFF_Q + 0], q1 = lds[OFF_Q + 1];
    const float q2 = lds[OFF_Q + 2], q3 = lds[OFF_Q + 3];

    // ================= decoder: 2 bands of 16 rows ==========================
    for (int band = 0; band < 2; ++band) {
        const int y0 = band * 16;

        // fc2 -> h3 window rows y0-2..y0+17 (8ch x 20 rows), OOB -> 0
        for (int i = tid; i < 5120; i += T) {
            int c = i / 640, rem = i - c * 640, r = rem >> 5, cx = rem & 31;
            int gy = y0 - 2 + r;
            float v = 0.f;
            if (gy >= 0 && gy < 32) {
                int idx = c * 1024 + gy * 32 + cx;
                const float4 wv = *reinterpret_cast<const float4*>(f2w + idx * 4);
                v = f2b[idx];
                v = fmaf(q0, wv.x, v);
                v = fmaf(q1, wv.y, v);
                v = fmaf(q2, wv.z, v);
                v = fmaf(q3, wv.w, v);
            }
            A[c * PSA + r * RS + 1 + cx] = v;
        }
        __syncthreads();

        // dconv1 8->16 rows y0-1..y0+16 (288 units)
        for (int u = tid; u < 288; u += T) {
            const int r1 = u >> 4, xb = (u & 15) * 2;
            const int gy = y0 - 1 + r1;
            float acc0[16], acc1[16];
            conv2px<8, 16, PSA>(A + r1 * RS + xb, d1w, d1b, acc0, acc1);
            const bool oob = (gy < 0) | (gy > 31);
            float* ob = Bf + r1 * RS + 1 + xb;
#pragma unroll
            for (int oc = 0; oc < 16; ++oc) {
                ob[oc * PSB]     = oob ? 0.f : fmaxf(acc0[oc], 0.f);
                ob[oc * PSB + 1] = oob ? 0.f : fmaxf(acc1[oc], 0.f);
            }
        }
        __syncthreads();

        // dconv2 16->3 + sigmoid -> global (256 units == T)
        {
            const int r = tid >> 4, xb = (tid & 15) * 2;
            float acc0[3], acc1[3];
            conv2px<16, 3, PSB>(Bf + r * RS + xb, d2w, d2b, acc0, acc1);
            float* ob = out + b * 3072 + (y0 + r) * 32 + xb;
#pragma unroll
            for (int oc = 0; oc < 3; ++oc) {
                float2 sv;
                sv.x = 1.f / (1.f + expf(-acc0[oc]));
                sv.y = 1.f / (1.f + expf(-acc1[oc]));
                *reinterpret_cast<float2*>(ob + oc * 1024) = sv;
            }
        }
        __syncthreads();
    }
}

// ---------------- launch ----------------------------------------------------
extern "C" void kernel_launch(void* const* d_in, const int* in_sizes, int n_in,
                              void* d_out, int out_size, void* d_ws, size_t ws_size,
                              hipStream_t stream) {
    const float* x   = (const float*)d_in[0];
    const float* c1w = (const float*)d_in[1];
    const float* c1b = (const float*)d_in[2];
    const float* c2w = (const float*)d_in[3];
    const float* c2b = (const float*)d_in[4];
    const float* fcw = (const float*)d_in[5];
    const float* fcb = (const float*)d_in[6];
    const float* qw  = (const float*)d_in[7];
    const float* f2w = (const float*)d_in[8];
    const float* f2b = (const float*)d_in[9];
    const float* d1w = (const float*)d_in[10];
    const float* d1b = (const float*)d_in[11];
    const float* d2w = (const float*)d_in[12];
    const float* d2b = (const float*)d_in[13];
    float* out = (float*)d_out;

    fused_kernel<<<2048, T, 0, stream>>>(
        x, c1w, c1b, c2w, c2b, fcw, fcb, qw, f2w, f2b,
        d1w, d1b, d2w, d2b, out);
}

// Round 5
// 235.952 us; speedup vs baseline: 11.2010x; 11.2010x over previous
//
#include <hip/hip_runtime.h>
#include <math.h>

#define T 1024
#define PS 1156                    // 34*34 plane
// region A: planes 0..7  (x in 0..2, h3 in 0..7)
// region B: planes 8..15 (h1 / h4 output-channel halves)
#define OFF_B   (8 * PS)
#define OFF_ROT (16 * PS)          // 96
#define OFF_ANG (OFF_ROT + 96)     // 4
#define OFF_Q   (OFF_ANG + 4)      // 4
#define OFF_RED (OFF_Q + 4)        // 64
#define LDS_FLOATS (OFF_RED + 64)  // 18664 floats = 74656 B -> 2 blocks/CU

// scalar 3x3 conv accumulate: NOC outputs, NIC input planes, weight row stride WSTR
// (same codegen pattern as the 40-VGPR R2 kernel: ds_read_b32 + uniform s_load weights)
template <int NIC, int NOC, int WSTR>
__device__ __forceinline__ void conv_acc(const float* __restrict__ ib,
                                         const float* __restrict__ wg,
                                         float* __restrict__ acc) {
#pragma unroll 2
    for (int ic = 0; ic < NIC; ++ic) {
        float v[9];
#pragma unroll
        for (int ky = 0; ky < 3; ++ky)
#pragma unroll
            for (int kx = 0; kx < 3; ++kx)
                v[ky * 3 + kx] = ib[ic * PS + ky * 34 + kx];
#pragma unroll
        for (int oc = 0; oc < NOC; ++oc) {
            const float* wp = wg + oc * WSTR + ic * 9;
#pragma unroll
            for (int k = 0; k < 9; ++k)
                acc[oc] = fmaf(wp[k], v[k], acc[oc]);
        }
    }
}

__global__ __launch_bounds__(T, 8) void fused_kernel(
    const float* __restrict__ x,
    const float* __restrict__ c1w, const float* __restrict__ c1b,
    const float* __restrict__ c2w, const float* __restrict__ c2b,
    const float* __restrict__ fcw, const float* __restrict__ fcb,
    const float* __restrict__ qw,
    const float* __restrict__ f2w, const float* __restrict__ f2b,
    const float* __restrict__ d1w, const float* __restrict__ d1b,
    const float* __restrict__ d2w, const float* __restrict__ d2b,
    float* __restrict__ out) {
    extern __shared__ float lds[];
    float* A   = lds;            // 8 planes
    float* Bf  = lds + OFF_B;    // 8 planes
    float* ROT = lds + OFF_ROT;

    const int tid = threadIdx.x;
    const int b   = blockIdx.x;
    const int py  = tid >> 5, px = tid & 31;       // this thread's pixel
    const int wbase = py * 34 + px;                // 3x3 window top-left (padded)
    const int ibase = (py + 1) * 34 + (px + 1);    // interior cell

    for (int i = tid; i < LDS_FLOATS; i += T) lds[i] = 0.f;   // halos must be 0
    __syncthreads();

    if (tid < 12) {   // Rot matrices (batch-independent, tiny)
        float phi = qw[tid * 3 + 0], theta = qw[tid * 3 + 1], omega = qw[tid * 3 + 2];
        float a = 0.5f * (phi + omega), d = 0.5f * (phi - omega);
        float st, ct; sincosf(0.5f * theta, &st, &ct);
        float sa, ca; sincosf(a, &sa, &ca);
        float sd, cd; sincosf(d, &sd, &cd);
        float* o = ROT + tid * 8;
        o[0] = ct * ca;  o[1] = -ct * sa;
        o[2] = -st * cd; o[3] = -st * sd;
        o[4] = st * cd;  o[5] = -st * sd;
        o[6] = ct * ca;  o[7] = ct * sa;
    }

    // ---- load x (3,32,32) into A planes 0..2 interior ----
    const float* xb = x + b * 3072;
#pragma unroll
    for (int k = 0; k < 3; ++k) {
        int i = tid + k * T;                       // 3072 = 3*T exactly
        int c = i >> 10, p = i & 1023;
        A[c * PS + ((p >> 5) + 1) * 34 + (p & 31) + 1] = xb[i];
    }
    __syncthreads();

    float acc2[8];                                 // conv2 accumulator (lives in regs)
#pragma unroll
    for (int oc = 0; oc < 8; ++oc) acc2[oc] = c2b[oc];
    float part[4] = {0.f, 0.f, 0.f, 0.f};          // fc partials

    // ---- conv1 half0 (oc 0..7) -> B ----
    {
        float a1[8];
#pragma unroll
        for (int oc = 0; oc < 8; ++oc) a1[oc] = c1b[oc];
        conv_acc<3, 8, 27>(A + wbase, c1w, a1);
#pragma unroll
        for (int oc = 0; oc < 8; ++oc) Bf[oc * PS + ibase] = fmaxf(a1[oc], 0.f);
    }
    __syncthreads();
    // ---- conv2 partial over ic 0..7 ----
    conv_acc<8, 8, 144>(Bf + wbase, c2w, acc2);
    __syncthreads();
    // ---- conv1 half1 (oc 8..15) -> B (overwrite) ----
    {
        float a1[8];
#pragma unroll
        for (int oc = 0; oc < 8; ++oc) a1[oc] = c1b[8 + oc];
        conv_acc<3, 8, 27>(A + wbase, c1w + 8 * 27, a1);
#pragma unroll
        for (int oc = 0; oc < 8; ++oc) Bf[oc * PS + ibase] = fmaxf(a1[oc], 0.f);
    }
    __syncthreads();
    // ---- conv2 partial over ic 8..15, then relu + fc fold ----
    conv_acc<8, 8, 144>(Bf + wbase, c2w + 8 * 9, acc2);
    {
#pragma unroll
        for (int oc = 0; oc < 8; ++oc) {
            const float h = fmaxf(acc2[oc], 0.f);
            const int gj = oc * 1024 + tid;        // h2 flat index (c,y,x)
#pragma unroll
            for (int o = 0; o < 4; ++o)
                part[o] = fmaf(h, fcw[o * 8192 + gj], part[o]);
        }
    }

    // ---- fc reduce -> angles ----
#pragma unroll
    for (int off = 32; off; off >>= 1)
#pragma unroll
        for (int o = 0; o < 4; ++o)
            part[o] += __shfl_down(part[o], off);
    if ((tid & 63) == 0) {
        int wid = tid >> 6;
#pragma unroll
        for (int o = 0; o < 4; ++o) lds[OFF_RED + wid * 4 + o] = part[o];
    }
    __syncthreads();
    if (tid == 0) {
#pragma unroll
        for (int o = 0; o < 4; ++o) {
            float s = fcb[o];
            for (int w = 0; w < 16; ++w) s += lds[OFF_RED + w * 4 + o];
            lds[OFF_ANG + o] = s;
        }
    }
    __syncthreads();

    // ---- 4-qubit statevector sim (wave 0) ----
    if (tid < 64) {
        const int s = tid & 15;
        float re = (s == 0) ? 1.f : 0.f, im = 0.f;
#pragma unroll
        for (int w = 0; w < 4; ++w) {
            float a = lds[OFF_ANG + w] * 0.5f;
            float sn, c; sincosf(a, &sn, &c);
            int stride = 1 << (3 - w);
            float pr = __shfl_xor(re, stride);
            float pi = __shfl_xor(im, stride);
            float nre = c * re + sn * pi;
            float nim = c * im - sn * pr;
            re = nre; im = nim;
        }
#pragma unroll
        for (int l = 0; l < 3; ++l) {
#pragma unroll
            for (int w = 0; w < 4; ++w) {
                const float* U = ROT + (l * 4 + w) * 8;
                int stride = 1 << (3 - w);
                bool bit = (s & stride) != 0;
                float pr = __shfl_xor(re, stride);
                float pi = __shfl_xor(im, stride);
                float cAr = bit ? U[6] : U[0], cAi = bit ? U[7] : U[1];
                float cBr = bit ? U[4] : U[2], cBi = bit ? U[5] : U[3];
                float nre = cAr * re - cAi * im + cBr * pr - cBi * pi;
                float nim = cAr * im + cAi * re + cBr * pi + cBi * pr;
                re = nre; im = nim;
            }
            const int r = (l % 3) + 1;
#pragma unroll
            for (int w = 0; w < 4; ++w) {
                int cs = 1 << (3 - w);
                int ts = 1 << (3 - ((w + r) & 3));
                float pr = __shfl_xor(re, ts);
                float pi = __shfl_xor(im, ts);
                if (s & cs) { re = pr; im = pi; }
            }
        }
        float pprob = re * re + im * im;
        float ev[4];
#pragma unroll
        for (int w = 0; w < 4; ++w)
            ev[w] = (s & (1 << (3 - w))) ? -pprob : pprob;
#pragma unroll
        for (int m = 1; m <= 8; m <<= 1)
#pragma unroll
            for (int w = 0; w < 4; ++w)
                ev[w] += __shfl_xor(ev[w], m);
        if (tid == 0) {
#pragma unroll
            for (int w = 0; w < 4; ++w) lds[OFF_Q + w] = ev[w];
        }
    }
    __syncthreads();

    const float q0 = lds[OFF_Q + 0], q1 = lds[OFF_Q + 1];
    const float q2 = lds[OFF_Q + 2], q3 = lds[OFF_Q + 3];

    // ---- fc2 -> h3 into A planes 0..7 interior ----
#pragma unroll
    for (int k = 0; k < 8; ++k) {
        int i = tid + k * T;                       // 8192 = 8*T exactly
        int c = i >> 10, p = i & 1023;
        const float4 wv = *reinterpret_cast<const float4*>(f2w + i * 4);
        float v = f2b[i];
        v = fmaf(q0, wv.x, v);
        v = fmaf(q1, wv.y, v);
        v = fmaf(q2, wv.z, v);
        v = fmaf(q3, wv.w, v);
        A[c * PS + ((p >> 5) + 1) * 34 + (p & 31) + 1] = v;
    }
    __syncthreads();

    float acc3[3];                                 // dconv2 accumulator (regs)
#pragma unroll
    for (int oc = 0; oc < 3; ++oc) acc3[oc] = d2b[oc];

    // ---- dconv1 half0 (oc 0..7) -> B ----
    {
        float a1[8];
#pragma unroll
        for (int oc = 0; oc < 8; ++oc) a1[oc] = d1b[oc];
        conv_acc<8, 8, 72>(A + wbase, d1w, a1);
#pragma unroll
        for (int oc = 0; oc < 8; ++oc) Bf[oc * PS + ibase] = fmaxf(a1[oc], 0.f);
    }
    __syncthreads();
    // ---- dconv2 partial over ic 0..7 ----
    conv_acc<8, 3, 144>(Bf + wbase, d2w, acc3);
    __syncthreads();
    // ---- dconv1 half1 (oc 8..15) -> B ----
    {
        float a1[8];
#pragma unroll
        for (int oc = 0; oc < 8; ++oc) a1[oc] = d1b[8 + oc];
        conv_acc<8, 8, 72>(A + wbase, d1w + 8 * 72, a1);
#pragma unroll
        for (int oc = 0; oc < 8; ++oc) Bf[oc * PS + ibase] = fmaxf(a1[oc], 0.f);
    }
    __syncthreads();
    // ---- dconv2 partial over ic 8..15 -> sigmoid -> out ----
    conv_acc<8, 3, 144>(Bf + wbase, d2w + 8 * 9, acc3);
    {
        float* ob = out + b * 3072 + tid;
#pragma unroll
        for (int oc = 0; oc < 3; ++oc)
            ob[oc * 1024] = 1.f / (1.f + expf(-acc3[oc]));
    }
}

// ---------------- launch ----------------------------------------------------
extern "C" void kernel_launch(void* const* d_in, const int* in_sizes, int n_in,
                              void* d_out, int out_size, void* d_ws, size_t ws_size,
                              hipStream_t stream) {
    const float* x   = (const float*)d_in[0];
    const float* c1w = (const float*)d_in[1];
    const float* c1b = (const float*)d_in[2];
    const float* c2w = (const float*)d_in[3];
    const float* c2b = (const float*)d_in[4];
    const float* fcw = (const float*)d_in[5];
    const float* fcb = (const float*)d_in[6];
    const float* qw  = (const float*)d_in[7];
    const float* f2w = (const float*)d_in[8];
    const float* f2b = (const float*)d_in[9];
    const float* d1w = (const float*)d_in[10];
    const float* d1b = (const float*)d_in[11];
    const float* d2w = (const float*)d_in[12];
    const float* d2b = (const float*)d_in[13];
    float* out = (float*)d_out;

    const size_t smem = LDS_FLOATS * sizeof(float);   // 74656 B -> 2 blocks/CU
    hipFuncSetAttribute((const void*)fused_kernel,
                        hipFuncAttributeMaxDynamicSharedMemorySize, (int)smem);
    fused_kernel<<<2048, T, smem, stream>>>(
        x, c1w, c1b, c2w, c2b, fcw, fcb, qw, f2w, f2b,
        d1w, d1b, d2w, d2b, out);
}

// Round 6
// 181.524 us; speedup vs baseline: 14.5595x; 1.2998x over previous
//
#include <hip/hip_runtime.h>
#include <math.h>

#define T 1024
#define PS 1156                    // 34*34 plane
#define OFF_B   (3 * PS)           // planes 3..10: conv1/h4 halves (8 planes)
#define OFF_ROT (11 * PS)          // 96
#define OFF_ANG (OFF_ROT + 96)
#define OFF_Q   (OFF_ANG + 4)
#define OFF_RED (OFF_Q + 4)        // 64
#define LDS_FLOATS (OFF_RED + 64)  // 12884 floats = 51536 B -> 2 blocks/CU

#define ZSZ (4 * 5 * 1024 * 4)     // 81920 floats: Z[quad g][j][pix] as float4
// fcwT lives at ws + ZSZ: 8192 float4 (32768 floats). total ws = 448 KB

// scalar 3x3 conv accumulate (known-good codegen: ds_read_b32 + uniform s_load)
template <int NIC, int NOC, int WSTR>
__device__ __forceinline__ void conv_acc(const float* __restrict__ ib,
                                         const float* __restrict__ wg,
                                         float* __restrict__ acc) {
#pragma unroll 2
    for (int ic = 0; ic < NIC; ++ic) {
        float v[9];
#pragma unroll
        for (int ky = 0; ky < 3; ++ky)
#pragma unroll
            for (int kx = 0; kx < 3; ++kx)
                v[ky * 3 + kx] = ib[ic * PS + ky * 34 + kx];
#pragma unroll
        for (int oc = 0; oc < NOC; ++oc) {
            const float* wp = wg + oc * WSTR + ic * 9;
#pragma unroll
            for (int k = 0; k < 9; ++k)
                acc[oc] = fmaf(wp[k], v[k], acc[oc]);
        }
    }
}

// ---- prep 1: decoder basis Z[g][j][pix] = conv3x3(F_j, d1w) (+d1b for j=4) ----
__global__ __launch_bounds__(T) void prep_z_kernel(
    const float* __restrict__ f2w, const float* __restrict__ f2b,
    const float* __restrict__ d1w, const float* __restrict__ d1b,
    float* __restrict__ ws) {
    __shared__ float F[8 * PS];
    const int tid = threadIdx.x;
    const int j = blockIdx.x;                 // 0..4 (4 = bias basis)
    const int py = tid >> 5, px = tid & 31;
    const int wbase = py * 34 + px;
    const int ibase = (py + 1) * 34 + (px + 1);

    for (int i = tid; i < 8 * PS; i += T) F[i] = 0.f;
    __syncthreads();
#pragma unroll
    for (int c = 0; c < 8; ++c) {
        const int idx = c * 1024 + tid;
        F[c * PS + ibase] = (j < 4) ? f2w[idx * 4 + j] : f2b[idx];
    }
    __syncthreads();
    float a1[16];
#pragma unroll
    for (int oc = 0; oc < 16; ++oc) a1[oc] = (j == 4) ? d1b[oc] : 0.f;
    conv_acc<8, 16, 72>(F + wbase, d1w, a1);
#pragma unroll
    for (int g = 0; g < 4; ++g) {
        float4 v = make_float4(a1[4 * g], a1[4 * g + 1], a1[4 * g + 2], a1[4 * g + 3]);
        *reinterpret_cast<float4*>(ws + ((g * 5 + j) * 1024 + tid) * 4) = v;
    }
}

// ---- prep 2: fcwT[gj] = float4{fcw[o*8192+gj]} ----
__global__ __launch_bounds__(T) void prep_fcwt_kernel(
    const float* __restrict__ fcw, float* __restrict__ fcwT) {
    const int i = blockIdx.x * T + threadIdx.x;   // 0..8191
#pragma unroll
    for (int o = 0; o < 4; ++o)
        fcwT[i * 4 + o] = fcw[o * 8192 + i];
}

// ---------------- fused per-image kernel -----------------------------------
__global__ __launch_bounds__(T, 8) void fused_kernel(
    const float* __restrict__ x,
    const float* __restrict__ c1w, const float* __restrict__ c1b,
    const float* __restrict__ c2w, const float* __restrict__ c2b,
    const float* __restrict__ fcb,
    const float* __restrict__ qw,
    const float* __restrict__ d2w, const float* __restrict__ d2b,
    const float* __restrict__ ws,     // Z basis + fcwT
    float* __restrict__ out) {
    __shared__ float lds[LDS_FLOATS];
    float* A   = lds;            // 3 planes: x
    float* Bf  = lds + OFF_B;    // 8 planes: conv1 halves / h4 halves
    float* ROT = lds + OFF_ROT;
    const float* fcwT = ws + ZSZ;

    const int tid = threadIdx.x;
    const int b   = blockIdx.x;
    const int py  = tid >> 5, px = tid & 31;
    const int wbase = py * 34 + px;
    const int ibase = (py + 1) * 34 + (px + 1);

    for (int i = tid; i < LDS_FLOATS; i += T) lds[i] = 0.f;   // halos must be 0
    __syncthreads();

    if (tid < 12) {   // Rot matrices (batch-independent, tiny)
        float phi = qw[tid * 3 + 0], theta = qw[tid * 3 + 1], omega = qw[tid * 3 + 2];
        float a = 0.5f * (phi + omega), d = 0.5f * (phi - omega);
        float st, ct; sincosf(0.5f * theta, &st, &ct);
        float sa, ca; sincosf(a, &sa, &ca);
        float sd, cd; sincosf(d, &sd, &cd);
        float* o = ROT + tid * 8;
        o[0] = ct * ca;  o[1] = -ct * sa;
        o[2] = -st * cd; o[3] = -st * sd;
        o[4] = st * cd;  o[5] = -st * sd;
        o[6] = ct * ca;  o[7] = ct * sa;
    }

    // ---- load x (3,32,32) into A interior ----
    const float* xb = x + b * 3072;
#pragma unroll
    for (int k = 0; k < 3; ++k) {
        int i = tid + k * T;
        int c = i >> 10, p = i & 1023;
        A[c * PS + ((p >> 5) + 1) * 34 + (p & 31) + 1] = xb[i];
    }
    __syncthreads();

    float acc2[8];
#pragma unroll
    for (int oc = 0; oc < 8; ++oc) acc2[oc] = c2b[oc];
    float part[4] = {0.f, 0.f, 0.f, 0.f};

    // ---- conv1 half0 (oc 0..7) -> B ----
    {
        float a1[8];
#pragma unroll
        for (int oc = 0; oc < 8; ++oc) a1[oc] = c1b[oc];
        conv_acc<3, 8, 27>(A + wbase, c1w, a1);
#pragma unroll
        for (int oc = 0; oc < 8; ++oc) Bf[oc * PS + ibase] = fmaxf(a1[oc], 0.f);
    }
    __syncthreads();
    conv_acc<8, 8, 144>(Bf + wbase, c2w, acc2);          // conv2 partial ic 0..7
    __syncthreads();
    // ---- conv1 half1 (oc 8..15) -> B ----
    {
        float a1[8];
#pragma unroll
        for (int oc = 0; oc < 8; ++oc) a1[oc] = c1b[8 + oc];
        conv_acc<3, 8, 27>(A + wbase, c1w + 8 * 27, a1);
#pragma unroll
        for (int oc = 0; oc < 8; ++oc) Bf[oc * PS + ibase] = fmaxf(a1[oc], 0.f);
    }
    __syncthreads();
    conv_acc<8, 8, 144>(Bf + wbase, c2w + 8 * 9, acc2);  // conv2 partial ic 8..15
    // ---- relu + fc fold (float4 fcwT) ----
#pragma unroll
    for (int oc = 0; oc < 8; ++oc) {
        const float h = fmaxf(acc2[oc], 0.f);
        const float4 wv = *reinterpret_cast<const float4*>(fcwT + (oc * 1024 + tid) * 4);
        part[0] = fmaf(h, wv.x, part[0]);
        part[1] = fmaf(h, wv.y, part[1]);
        part[2] = fmaf(h, wv.z, part[2]);
        part[3] = fmaf(h, wv.w, part[3]);
    }

    // ---- fc reduce -> angles ----
#pragma unroll
    for (int off = 32; off; off >>= 1)
#pragma unroll
        for (int o = 0; o < 4; ++o)
            part[o] += __shfl_down(part[o], off);
    if ((tid & 63) == 0) {
        int wid = tid >> 6;
#pragma unroll
        for (int o = 0; o < 4; ++o) lds[OFF_RED + wid * 4 + o] = part[o];
    }
    __syncthreads();
    if (tid == 0) {
#pragma unroll
        for (int o = 0; o < 4; ++o) {
            float s = fcb[o];
            for (int w = 0; w < 16; ++w) s += lds[OFF_RED + w * 4 + o];
            lds[OFF_ANG + o] = s;
        }
    }
    __syncthreads();

    // ---- 4-qubit statevector sim (wave 0) ----
    if (tid < 64) {
        const int s = tid & 15;
        float re = (s == 0) ? 1.f : 0.f, im = 0.f;
#pragma unroll
        for (int w = 0; w < 4; ++w) {
            float a = lds[OFF_ANG + w] * 0.5f;
            float sn, c; sincosf(a, &sn, &c);
            int stride = 1 << (3 - w);
            float pr = __shfl_xor(re, stride);
            float pi = __shfl_xor(im, stride);
            float nre = c * re + sn * pi;
            float nim = c * im - sn * pr;
            re = nre; im = nim;
        }
#pragma unroll
        for (int l = 0; l < 3; ++l) {
#pragma unroll
            for (int w = 0; w < 4; ++w) {
                const float* U = ROT + (l * 4 + w) * 8;
                int stride = 1 << (3 - w);
                bool bit = (s & stride) != 0;
                float pr = __shfl_xor(re, stride);
                float pi = __shfl_xor(im, stride);
                float cAr = bit ? U[6] : U[0], cAi = bit ? U[7] : U[1];
                float cBr = bit ? U[4] : U[2], cBi = bit ? U[5] : U[3];
                float nre = cAr * re - cAi * im + cBr * pr - cBi * pi;
                float nim = cAr * im + cAi * re + cBr * pi + cBi * pr;
                re = nre; im = nim;
            }
            const int r = (l % 3) + 1;
#pragma unroll
            for (int w = 0; w < 4; ++w) {
                int cs = 1 << (3 - w);
                int ts = 1 << (3 - ((w + r) & 3));
                float pr = __shfl_xor(re, ts);
                float pi = __shfl_xor(im, ts);
                if (s & cs) { re = pr; im = pi; }
            }
        }
        float pprob = re * re + im * im;
        float ev[4];
#pragma unroll
        for (int w = 0; w < 4; ++w)
            ev[w] = (s & (1 << (3 - w))) ? -pprob : pprob;
#pragma unroll
        for (int m = 1; m <= 8; m <<= 1)
#pragma unroll
            for (int w = 0; w < 4; ++w)
                ev[w] += __shfl_xor(ev[w], m);
        if (tid == 0) {
#pragma unroll
            for (int w = 0; w < 4; ++w) lds[OFF_Q + w] = ev[w];
        }
    }
    __syncthreads();

    const float qv[5] = {lds[OFF_Q + 0], lds[OFF_Q + 1],
                         lds[OFF_Q + 2], lds[OFF_Q + 3], 1.f};

    // ---- decoder: h4 halves from rank-5 basis, dconv2 partials ----
    float acc3[3];
#pragma unroll
    for (int oc = 0; oc < 3; ++oc) acc3[oc] = d2b[oc];

#pragma unroll
    for (int h = 0; h < 2; ++h) {
#pragma unroll
        for (int gg = 0; gg < 2; ++gg) {
            const int g = h * 2 + gg;
            float4 a = make_float4(0.f, 0.f, 0.f, 0.f);
#pragma unroll
            for (int j = 0; j < 5; ++j) {
                const float4 zv = *reinterpret_cast<const float4*>(
                    ws + ((g * 5 + j) * 1024 + tid) * 4);
                a.x = fmaf(qv[j], zv.x, a.x);
                a.y = fmaf(qv[j], zv.y, a.y);
                a.z = fmaf(qv[j], zv.z, a.z);
                a.w = fmaf(qv[j], zv.w, a.w);
            }
            Bf[(gg * 4 + 0) * PS + ibase] = fmaxf(a.x, 0.f);
            Bf[(gg * 4 + 1) * PS + ibase] = fmaxf(a.y, 0.f);
            Bf[(gg * 4 + 2) * PS + ibase] = fmaxf(a.z, 0.f);
            Bf[(gg * 4 + 3) * PS + ibase] = fmaxf(a.w, 0.f);
        }
        __syncthreads();
        conv_acc<8, 3, 144>(Bf + wbase, d2w + h * 72, acc3);
        if (h == 0) __syncthreads();   // protect half1's B overwrite
    }

    // ---- sigmoid -> out ----
    {
        float* ob = out + b * 3072 + tid;
#pragma unroll
        for (int oc = 0; oc < 3; ++oc)
            ob[oc * 1024] = 1.f / (1.f + expf(-acc3[oc]));
    }
}

// ---------------- launch ----------------------------------------------------
extern "C" void kernel_launch(void* const* d_in, const int* in_sizes, int n_in,
                              void* d_out, int out_size, void* d_ws, size_t ws_size,
                              hipStream_t stream) {
    const float* x   = (const float*)d_in[0];
    const float* c1w = (const float*)d_in[1];
    const float* c1b = (const float*)d_in[2];
    const float* c2w = (const float*)d_in[3];
    const float* c2b = (const float*)d_in[4];
    const float* fcw = (const float*)d_in[5];
    const float* fcb = (const float*)d_in[6];
    const float* qw  = (const float*)d_in[7];
    const float* f2w = (const float*)d_in[8];
    const float* f2b = (const float*)d_in[9];
    const float* d1w = (const float*)d_in[10];
    const float* d1b = (const float*)d_in[11];
    const float* d2w = (const float*)d_in[12];
    const float* d2b = (const float*)d_in[13];
    float* out = (float*)d_out;
    float* ws  = (float*)d_ws;   // Z basis (81920 f) + fcwT (32768 f) = 448 KB

    prep_z_kernel<<<5, T, 0, stream>>>(f2w, f2b, d1w, d1b, ws);
    prep_fcwt_kernel<<<8, T, 0, stream>>>(fcw, ws + ZSZ);
    fused_kernel<<<2048, T, 0, stream>>>(
        x, c1w, c1b, c2w, c2b, fcb, qw, d2w, d2b, ws, out);
}